// Round 18
// baseline (471.396 us; speedup 1.0000x reference)
//
#include <hip/hip_runtime.h>
#include <stdint.h>
#include <stddef.h>

#define DH 128
#define CHUNK 4096          // edges per partition block
#define PBK_SHIFT 9         // 512 nodes per bucket
#define NBKMAX 224          // supports N <= 114688

typedef short v8s __attribute__((ext_vector_type(8)));
typedef float v4f __attribute__((ext_vector_type(4)));
typedef float v2f __attribute__((ext_vector_type(2)));

static __device__ __forceinline__ float bf2f(uint16_t h) {
    union { uint32_t i; float f; } u; u.i = ((uint32_t)h) << 16; return u.f;
}
static __device__ __forceinline__ uint16_t f2bf(float f) {
    union { float f; uint32_t i; } u; u.f = f;
    uint32_t r = u.i + 0x7fffu + ((u.i >> 16) & 1u);  // RNE
    return (uint16_t)(r >> 16);
}
static __device__ __forceinline__ float loadf(const void* p, size_t i, bool f32) {
    return f32 ? ((const float*)p)[i] : bf2f(((const uint16_t*)p)[i]);
}
static __device__ __forceinline__ uint16_t pack_fp8x2(float a, float b) {
    return (uint16_t)(__builtin_amdgcn_cvt_pk_fp8_f32(a, b, 0, false) & 0xFFFF);
}

// ---------- histogram (+ dtype detect in block 0) ----------
__global__ void histA_k(const int* __restrict__ dst, const uint32_t* w, int* flag,
                        int* gh, int E, int n, int GH, int nbk) {
    __shared__ int h[NBKMAX];
    int t = threadIdx.x;
    if (blockIdx.x == 0 && t < 64) {
        int hits = 0;
        for (int k = 0; k < 4; ++k) {
            uint32_t u = w[t * 4 + k];
            int e = (u >> 7) & 0xFF;
            hits += (e >= 100 && e <= 130) ? 1 : 0;
        }
        for (int off = 32; off; off >>= 1) hits += __shfl_down(hits, off);
        if (t == 0) *flag = (hits >= 128) ? 0 : 1;   // 0 = bf16, 1 = fp32
    }
    int base = blockIdx.x * CHUNK;
    for (int i = t; i < NBKMAX; i += 256) h[i] = 0;
    __syncthreads();
    for (int it = 0; it < CHUNK / 256; ++it) {
        int e = base + it * 256 + t;
        if (e < E) {
            int d = dst[e];
            if ((unsigned)d < (unsigned)n) atomicAdd(&h[d >> PBK_SHIFT], 1);
        }
    }
    __syncthreads();
    for (int b = t; b < nbk; b += 256) gh[b * GH + blockIdx.x] = h[b];
}

// ---------- convert x -> bf16 (if fp32) + fp8 table, weights -> bf16 ----------
__global__ void cvtall_k(const void* x, const void* wl0, const void* wr0,
                         const void* wl1, const void* wr1, const void* b0,
                         const void* b1, const int* dt, uint16_t* xb,
                         uint16_t* xq8, uint16_t* wcvt, int nxh) {
    int i = blockIdx.x * 256 + threadIdx.x;
    bool f32 = (*dt != 0);
    if (i < nxh) {
        float v0, v1;
        if (f32) {
            const float2 v = ((const float2*)x)[i];
            v0 = v.x; v1 = v.y;
            ((uint32_t*)xb)[i] = (uint32_t)f2bf(v0) | ((uint32_t)f2bf(v1) << 16);
        } else {
            uint32_t u = ((const uint32_t*)x)[i];
            v0 = bf2f((uint16_t)u); v1 = bf2f((uint16_t)(u >> 16));
        }
        xq8[i] = pack_fp8x2(v0, v1);
        return;
    }
    int j = i - nxh;
    const void* src; int off;
    if      (j < 16384) { src = wl0; off = j; }
    else if (j < 32768) { src = wr0; off = j - 16384; }
    else if (j < 49152) { src = wl1; off = j - 32768; }
    else if (j < 65536) { src = wr1; off = j - 49152; }
    else if (j < 65664) { src = b0;  off = j - 65536; }
    else if (j < 65792) { src = b1;  off = j - 65664; }
    else return;
    wcvt[j] = f32 ? f2bf(((const float*)src)[off]) : ((const uint16_t*)src)[off];
}

// ---------- coalesced H16 -> fp8 table (fixes R17's byte-scatter epilogue) ----------
__global__ void cvt8_k(const uint32_t* __restrict__ H32, uint16_t* __restrict__ q8,
                       int nxh) {
    int i = blockIdx.x * 256 + threadIdx.x;
    if (i >= nxh) return;
    uint32_t u = H32[i];
    q8[i] = pack_fp8x2(bf2f((uint16_t)u), bf2f((uint16_t)(u >> 16)));
}

// ---------- scans over flattened bucket-major gh ----------
__global__ void scan1_k(const int* cnt, int* bsum, int n) {
    __shared__ int wt[4];
    int t = threadIdx.x, lane = t & 63, wv = t >> 6;
    int i = blockIdx.x * 256 + t;
    int v = (i < n) ? cnt[i] : 0;
    for (int off = 32; off; off >>= 1) v += __shfl_down(v, off);
    if (lane == 0) wt[wv] = v;
    __syncthreads();
    if (t == 0) bsum[blockIdx.x] = wt[0] + wt[1] + wt[2] + wt[3];
}

__global__ void scan2_k(const int* bsum, int* boff, int* row_n, int nb) {
    __shared__ int wt[4];
    __shared__ int carry_s;
    int t = threadIdx.x, lane = t & 63, wv = t >> 6;
    if (t == 0) carry_s = 0;
    __syncthreads();
    for (int base = 0; base < nb; base += 256) {
        int i = base + t;
        int c = (i < nb) ? bsum[i] : 0;
        int v = c;
        for (int off = 1; off < 64; off <<= 1) {
            int u = __shfl_up(v, off);
            if (lane >= off) v += u;
        }
        if (lane == 63) wt[wv] = v;
        __syncthreads();
        int woff = 0;
        for (int w = 0; w < wv; ++w) woff += wt[w];
        int total = wt[0] + wt[1] + wt[2] + wt[3];
        int carry = carry_s;
        if (i < nb) boff[i] = carry + woff + (v - c);
        __syncthreads();
        if (t == 0) carry_s = carry + total;
        __syncthreads();
    }
    if (t == 0) *row_n = carry_s;
}

__global__ void scanG3_k(const int* in, const int* boff, int* out, int n) {
    __shared__ int wt[4];
    int t = threadIdx.x, lane = t & 63, wv = t >> 6;
    int i = blockIdx.x * 256 + t;
    int c = (i < n) ? in[i] : 0;
    int v = c;
    for (int off = 1; off < 64; off <<= 1) {
        int u = __shfl_up(v, off);
        if (lane >= off) v += u;
    }
    if (lane == 63) wt[wv] = v;
    __syncthreads();
    int woff = 0;
    for (int w = 0; w < wv; ++w) woff += wt[w];
    if (i < n) out[i] = boff[blockIdx.x] + woff + (v - c);
}

// ---------- scatter with precomputed offsets (no global atomics) ----------
__global__ void scatB_k(const int* __restrict__ src, const int* __restrict__ dst,
                        const int* __restrict__ ghs, uint32_t* gbuf,
                        int E, int n, int GH, int nbk) {
    __shared__ int cur[NBKMAX];
    int t = threadIdx.x;
    int base = blockIdx.x * CHUNK;
    for (int b = t; b < nbk; b += 256) cur[b] = ghs[b * GH + blockIdx.x];
    __syncthreads();
    for (int it = 0; it < CHUNK / 256; ++it) {
        int e = base + it * 256 + t;
        if (e < E) {
            int d = dst[e];
            if ((unsigned)d < (unsigned)n) {
                int s = src[e];
                int slot = atomicAdd(&cur[d >> PBK_SHIFT], 1);
                uint32_t rec = ((uint32_t)(d & 511) << 17) | (uint32_t)s;
                __builtin_nontemporal_store(rec, &gbuf[slot]);
            }
        }
    }
}

// ---------- per-bucket regroup (512 nodes/bucket) ----------
__global__ void regroupC_k(const uint32_t* __restrict__ gbuf, const int* ghs,
                           const int* __restrict__ totalp, int GH,
                           int* row_start, float* inv_deg, int* csr_src,
                           int n, int nbk) {
    __shared__ int lcnt[512];
    __shared__ int rs[512];
    __shared__ int wsum[4];
    int b = blockIdx.x, t = threadIdx.x, lane = t & 63, wv = t >> 6;
    int node0 = b << PBK_SHIFT;
    int nn = n - node0; if (nn > 512) nn = 512;
    int start = ghs[b * GH];
    int end = (b + 1 < nbk) ? ghs[(b + 1) * GH] : *totalp;
    for (int i = t; i < 512; i += 256) lcnt[i] = 0;
    __syncthreads();
    for (int i = start + t; i < end; i += 256)
        atomicAdd(&lcnt[gbuf[i] >> 17], 1);
    __syncthreads();
    int c0 = lcnt[2 * t], c1 = lcnt[2 * t + 1];
    int s = c0 + c1;
    int v = s;
    for (int off = 1; off < 64; off <<= 1) {
        int u = __shfl_up(v, off);
        if (lane >= off) v += u;
    }
    if (lane == 63) wsum[wv] = v;
    __syncthreads();
    int woff = 0;
    for (int w = 0; w < wv; ++w) woff += wsum[w];
    int ex = woff + (v - s);
    rs[2 * t]     = ex;
    rs[2 * t + 1] = ex + c0;
    __syncthreads();
    for (int i = t; i < nn; i += 256) {
        row_start[node0 + i] = start + rs[i];
        inv_deg[node0 + i] = 1.0f / fmaxf((float)lcnt[i], 1.0f);
    }
    __syncthreads();
    for (int i = t; i < 512; i += 256) lcnt[i] = 0;   // reuse as cursors
    __syncthreads();
    for (int i = start + t; i < end; i += 256) {
        uint32_t rec = gbuf[i];
        int local = rec >> 17;
        int sv = rec & 0x1FFFF;
        int rank = atomicAdd(&lcnt[local], 1);
        csr_src[start + rs[local] + rank] = sv;
    }
}

// ---------- mean aggregation over FP8 table: one wave/node, 8 edges/iter ----------
__global__ void agg_k(const uint8_t* __restrict__ feat8,
                      const int* csr_src, const int* row_start,
                      const float* inv_deg, uint16_t* A, int n) {
    int wave = threadIdx.x >> 6, lane = threadIdx.x & 63;
    int node = blockIdx.x * 4 + wave;
    if (node >= n) return;
    int seg = lane & 7, sub = lane >> 3;
    int e0 = row_start[node], e1 = row_start[node + 1];
    float acc[16];
#pragma unroll
    for (int i = 0; i < 16; ++i) acc[i] = 0.f;
    for (int e = e0 + sub; e < e1; e += 8) {
        int s = csr_src[e];
        if ((unsigned)s >= (unsigned)n) continue;
        uint4 u = *(const uint4*)(feat8 + (size_t)s * 128 + seg * 16);
        v2f p;
        p = __builtin_amdgcn_cvt_pk_f32_fp8(u.x, false); acc[0]  += p.x; acc[1]  += p.y;
        p = __builtin_amdgcn_cvt_pk_f32_fp8(u.x, true);  acc[2]  += p.x; acc[3]  += p.y;
        p = __builtin_amdgcn_cvt_pk_f32_fp8(u.y, false); acc[4]  += p.x; acc[5]  += p.y;
        p = __builtin_amdgcn_cvt_pk_f32_fp8(u.y, true);  acc[6]  += p.x; acc[7]  += p.y;
        p = __builtin_amdgcn_cvt_pk_f32_fp8(u.z, false); acc[8]  += p.x; acc[9]  += p.y;
        p = __builtin_amdgcn_cvt_pk_f32_fp8(u.z, true);  acc[10] += p.x; acc[11] += p.y;
        p = __builtin_amdgcn_cvt_pk_f32_fp8(u.w, false); acc[12] += p.x; acc[13] += p.y;
        p = __builtin_amdgcn_cvt_pk_f32_fp8(u.w, true);  acc[14] += p.x; acc[15] += p.y;
    }
#pragma unroll
    for (int i = 0; i < 16; ++i) {
        acc[i] += __shfl_down(acc[i], 32);
        acc[i] += __shfl_down(acc[i], 16);
        acc[i] += __shfl_down(acc[i], 8);
    }
    if (sub == 0) {
        float sc = inv_deg[node];
        uint4 o0, o1;
        o0.x = (uint32_t)f2bf(acc[0]*sc)  | ((uint32_t)f2bf(acc[1]*sc)  << 16);
        o0.y = (uint32_t)f2bf(acc[2]*sc)  | ((uint32_t)f2bf(acc[3]*sc)  << 16);
        o0.z = (uint32_t)f2bf(acc[4]*sc)  | ((uint32_t)f2bf(acc[5]*sc)  << 16);
        o0.w = (uint32_t)f2bf(acc[6]*sc)  | ((uint32_t)f2bf(acc[7]*sc)  << 16);
        o1.x = (uint32_t)f2bf(acc[8]*sc)  | ((uint32_t)f2bf(acc[9]*sc)  << 16);
        o1.y = (uint32_t)f2bf(acc[10]*sc) | ((uint32_t)f2bf(acc[11]*sc) << 16);
        o1.z = (uint32_t)f2bf(acc[12]*sc) | ((uint32_t)f2bf(acc[13]*sc) << 16);
        o1.w = (uint32_t)f2bf(acc[14]*sc) | ((uint32_t)f2bf(acc[15]*sc) << 16);
        uint4* dst = (uint4*)A + (size_t)node * 16 + seg * 2;
        dst[0] = o0;
        dst[1] = o1;
    }
}

// ---------- fused dual MFMA dense ----------
// Mode A (tq=false): H16 = relu(X@Wr^T + A@Wl^T + b)  (no fp8 here — R17 lesson:
// byte-scatter epilogue caused 34MB write amp; fp8 copy now via cvt8_k).
// Mode B (tq=true):  only T = H@wl2^T, Q = H@wr2^T emitted (H store is dead).
__global__ void dense2_k(const uint16_t* __restrict__ X,
                         const uint16_t* __restrict__ Xalt, const int* xdt,
                         const uint16_t* __restrict__ A,
                         const uint16_t* __restrict__ Wr,
                         const uint16_t* __restrict__ Wl,
                         const uint16_t* __restrict__ bias,
                         uint16_t* __restrict__ H,
                         const void* wl2, const void* wr2, const int* wdt,
                         float* T, float* Q, int n) {
    const int lane = threadIdx.x & 63;
    const int wv = threadIdx.x >> 6;
    const int m0 = blockIdx.x * 128 + wv * 32;
    if (m0 >= n) return;
    const uint16_t* Xs = X;
    if (xdt != nullptr && *xdt == 0) Xs = Xalt;
    const bool tq = (T != nullptr);
    const bool wf = tq && (*wdt != 0);
    const int row16 = lane & 15, quad = lane >> 4;
    int mr0 = m0 + row16;      int ml0 = (mr0 < n) ? mr0 : (n - 1);
    int mr1 = m0 + 16 + row16; int ml1 = (mr1 < n) ? mr1 : (n - 1);
    v8s ax0[4], aa0[4], ax1[4], aa1[4];
    const uint16_t* xr0 = Xs + (size_t)ml0 * DH + quad * 8;
    const uint16_t* ar0 = A  + (size_t)ml0 * DH + quad * 8;
    const uint16_t* xr1 = Xs + (size_t)ml1 * DH + quad * 8;
    const uint16_t* ar1 = A  + (size_t)ml1 * DH + quad * 8;
#pragma unroll
    for (int kt = 0; kt < 4; ++kt) {
        ax0[kt] = *(const v8s*)(xr0 + kt * 32);
        aa0[kt] = *(const v8s*)(ar0 + kt * 32);
        ax1[kt] = *(const v8s*)(xr1 + kt * 32);
        aa1[kt] = *(const v8s*)(ar1 + kt * 32);
    }
    float tqa[4][8];   // [T0,T1,Q0,Q1][row slot]
    if (tq) {
#pragma unroll
        for (int a = 0; a < 4; ++a)
#pragma unroll
            for (int j = 0; j < 8; ++j) tqa[a][j] = 0.f;
    }
#pragma unroll
    for (int nt = 0; nt < 8; ++nt) {
        v4f acc0 = {0.f, 0.f, 0.f, 0.f};
        v4f acc1 = {0.f, 0.f, 0.f, 0.f};
        const uint16_t* wrr = Wr + (size_t)(nt * 16 + row16) * DH + quad * 8;
        const uint16_t* wlr = Wl + (size_t)(nt * 16 + row16) * DH + quad * 8;
#pragma unroll
        for (int kt = 0; kt < 4; ++kt) {
            v8s br = *(const v8s*)(wrr + kt * 32);
            acc0 = __builtin_amdgcn_mfma_f32_16x16x32_bf16(ax0[kt], br, acc0, 0, 0, 0);
            acc1 = __builtin_amdgcn_mfma_f32_16x16x32_bf16(ax1[kt], br, acc1, 0, 0, 0);
            v8s bl = *(const v8s*)(wlr + kt * 32);
            acc0 = __builtin_amdgcn_mfma_f32_16x16x32_bf16(aa0[kt], bl, acc0, 0, 0, 0);
            acc1 = __builtin_amdgcn_mfma_f32_16x16x32_bf16(aa1[kt], bl, acc1, 0, 0, 0);
        }
        int o = nt * 16 + row16;
        float bo = bf2f(bias[o]);
        float wl2_0 = 0.f, wl2_1 = 0.f, wr2_0 = 0.f, wr2_1 = 0.f;
        if (tq) {
            wl2_0 = loadf(wl2, o, wf);  wl2_1 = loadf(wl2, 128 + o, wf);
            wr2_0 = loadf(wr2, o, wf);  wr2_1 = loadf(wr2, 128 + o, wf);
        }
#pragma unroll
        for (int r = 0; r < 4; ++r) {
            int m = m0 + quad * 4 + r;
            float h0 = fmaxf(acc0[r] + bo, 0.0f);
            int m2 = m0 + 16 + quad * 4 + r;
            float h1 = fmaxf(acc1[r] + bo, 0.0f);
            if (tq) {
                tqa[0][r] += h0 * wl2_0; tqa[1][r] += h0 * wl2_1;
                tqa[2][r] += h0 * wr2_0; tqa[3][r] += h0 * wr2_1;
                tqa[0][4 + r] += h1 * wl2_0; tqa[1][4 + r] += h1 * wl2_1;
                tqa[2][4 + r] += h1 * wr2_0; tqa[3][4 + r] += h1 * wr2_1;
            } else {
                if (m < n)  H[(size_t)m * DH + o]  = f2bf(h0);
                if (m2 < n) H[(size_t)m2 * DH + o] = f2bf(h1);
            }
        }
    }
    if (tq) {
#pragma unroll
        for (int mbit = 1; mbit < 16; mbit <<= 1)
#pragma unroll
            for (int a = 0; a < 4; ++a)
#pragma unroll
                for (int j = 0; j < 8; ++j)
                    tqa[a][j] += __shfl_xor(tqa[a][j], mbit);
        if (row16 == 0) {
#pragma unroll
            for (int r = 0; r < 4; ++r) {
                int m = m0 + quad * 4 + r;
                if (m < n) {
                    T[(size_t)m * 2]     = tqa[0][r];
                    T[(size_t)m * 2 + 1] = tqa[1][r];
                    Q[(size_t)m * 2]     = tqa[2][r];
                    Q[(size_t)m * 2 + 1] = tqa[3][r];
                }
                int m2 = m0 + 16 + quad * 4 + r;
                if (m2 < n) {
                    T[(size_t)m2 * 2]     = tqa[0][4 + r];
                    T[(size_t)m2 * 2 + 1] = tqa[1][4 + r];
                    Q[(size_t)m2 * 2]     = tqa[2][4 + r];
                    Q[(size_t)m2 * 2 + 1] = tqa[3][4 + r];
                }
            }
        }
    }
}

// ---------- final: 2-wide CSR gather + log_softmax, fp32 out ----------
__global__ void final_k(const float* T, const float* Q, const int* row_start,
                        const int* csr_src, const float* inv_deg,
                        const void* b2, const int* wdt, float* out, int n) {
    int i = blockIdx.x * 256 + threadIdx.x;
    if (i >= n) return;
    bool f32 = (*wdt != 0);
    int e0 = row_start[i], e1 = row_start[i + 1];
    float s0 = 0.f, s1 = 0.f;
    const float2* T2 = (const float2*)T;
    for (int e = e0; e < e1; ++e) {
        int j = csr_src[e];
        if ((unsigned)j >= (unsigned)n) continue;
        float2 tv = T2[j];
        s0 += tv.x;
        s1 += tv.y;
    }
    float sc = inv_deg[i];
    float l0 = s0 * sc + loadf(b2, 0, f32) + Q[(size_t)i * 2];
    float l1 = s1 * sc + loadf(b2, 1, f32) + Q[(size_t)i * 2 + 1];
    float m = fmaxf(l0, l1);
    float lse = m + logf(expf(l0 - m) + expf(l1 - m));
    out[(size_t)i * 2]     = l0 - lse;
    out[(size_t)i * 2 + 1] = l1 - lse;
}

extern "C" void kernel_launch(void* const* d_in, const int* in_sizes, int n_in,
                              void* d_out, int out_size, void* d_ws, size_t ws_size,
                              hipStream_t stream) {
    int ix, iwl0, ib0, iwr0, iwl1, ib1, iwr1, iwl2, ib2, iwr2, iesrc, iedst;
    if (in_sizes[0] < 100000) {  // sorted-keys fallback
        ib0 = 0; ib1 = 1; ib2 = 2; iedst = 3; iesrc = 4;
        iwl0 = 5; iwl1 = 6; iwl2 = 7; iwr0 = 8; iwr1 = 9; iwr2 = 10; ix = 11;
    } else {                     // dict-insertion order (confirmed R7-R17)
        ix = 0; iwl0 = 1; ib0 = 2; iwr0 = 3; iwl1 = 4; ib1 = 5;
        iwr1 = 6; iwl2 = 7; ib2 = 8; iwr2 = 9; iesrc = 10; iedst = 11;
    }
    const void* x   = d_in[ix];
    const void* wl0 = d_in[iwl0];
    const void* b0  = d_in[ib0];
    const void* wr0 = d_in[iwr0];
    const void* wl1 = d_in[iwl1];
    const void* b1  = d_in[ib1];
    const void* wr1 = d_in[iwr1];
    const void* wl2 = d_in[iwl2];
    const void* b2  = d_in[ib2];
    const void* wr2 = d_in[iwr2];
    const int* esrc = (const int*)d_in[iesrc];
    const int* edst = (const int*)d_in[iedst];
    const int N = out_size / 2;
    const int E = in_sizes[iesrc];
    (void)n_in; (void)ws_size;

    char* ws = (char*)d_ws;
    size_t off = 0;
    auto carve = [&](size_t bytes) -> char* {
        char* p = ws + off;
        off = (off + bytes + 255) & ~(size_t)255;
        return p;
    };
    int gN = (N + 255) / 256;
    int GH = (E + CHUNK - 1) / CHUNK;
    int nbk = (N + 511) >> PBK_SHIFT;
    int n_scan = nbk * GH;
    int gS = (n_scan + 255) / 256;
    int* dtf        = (int*)   carve(256);
    int* gh         = (int*)   carve((size_t)n_scan * 4);
    int* ghs        = (int*)   carve((size_t)n_scan * 4);
    int* bsum       = (int*)   carve((size_t)gS * 4);
    int* boff       = (int*)   carve((size_t)gS * 4);
    uint32_t* gbuf  = (uint32_t*)carve((size_t)E * 4);
    int* row_start  = (int*)   carve((size_t)(N + 1) * 4);
    float* inv_deg  = (float*) carve((size_t)N * 4);
    int* csr_src    = (int*)   carve((size_t)E * 4);
    uint16_t* A16   = (uint16_t*)carve((size_t)N * DH * 2);
    uint16_t* H16   = (uint16_t*)carve((size_t)N * DH * 2);
    uint16_t* xb    = (uint16_t*)carve((size_t)N * DH * 2);
    uint8_t*  xq8   = (uint8_t*) carve((size_t)N * DH);
    uint8_t*  hq8   = (uint8_t*) carve((size_t)N * DH);
    uint16_t* wcvt  = (uint16_t*)carve(65792 * 2);
    float* T        = (float*) carve((size_t)N * 2 * 4);
    float* Q        = (float*) carve((size_t)N * 2 * 4);
    uint16_t* wl0b = wcvt;
    uint16_t* wr0b = wcvt + 16384;
    uint16_t* wl1b = wcvt + 32768;
    uint16_t* wr1b = wcvt + 49152;
    uint16_t* b0b  = wcvt + 65536;
    uint16_t* b1b  = wcvt + 65664;

    int ga = (N + 3) / 4;
    int gd = (N + 127) / 128;
    int nxh = (N * DH) / 2;
    int gc = (nxh + 65792 + 255) / 256;
    int g8 = (nxh + 255) / 256;

    // histogram (+dtype detect), then conversions (x pairs -> bf16 + fp8)
    histA_k<<<GH, 256, 0, stream>>>(edst, (const uint32_t*)wl0, dtf, gh, E, N, GH, nbk);
    cvtall_k<<<gc, 256, 0, stream>>>(x, wl0, wr0, wl1, wr1, b0, b1, dtf,
                                     xb, (uint16_t*)xq8, wcvt, nxh);

    // CSR build: radix partition with precomputed offsets
    scan1_k<<<gS, 256, 0, stream>>>(gh, bsum, n_scan);
    scan2_k<<<1, 256, 0, stream>>>(bsum, boff, &row_start[N], gS);
    scanG3_k<<<gS, 256, 0, stream>>>(gh, boff, ghs, n_scan);
    scatB_k<<<GH, 256, 0, stream>>>(esrc, edst, ghs, gbuf, E, N, GH, nbk);
    regroupC_k<<<nbk, 256, 0, stream>>>(gbuf, ghs, &row_start[N], GH,
                                        row_start, inv_deg, csr_src, N, nbk);

    // layer 0: A = agg(x_fp8); H16 = relu(x@Wr0^T + A@Wl0^T + b0)
    agg_k<<<ga, 256, 0, stream>>>(xq8, csr_src, row_start, inv_deg, A16, N);
    dense2_k<<<gd, 256, 0, stream>>>(xb, (const uint16_t*)x, dtf,
                                     A16, wr0b, wl0b, b0b, H16,
                                     nullptr, nullptr, nullptr,
                                     nullptr, nullptr, N);

    // coalesced H16 -> fp8 for layer-1 gather
    cvt8_k<<<g8, 256, 0, stream>>>((const uint32_t*)H16, (uint16_t*)hq8, nxh);

    // layer 1: A = agg(H_fp8); fused T/Q heads only (H store is dead)
    agg_k<<<ga, 256, 0, stream>>>(hq8, csr_src, row_start, inv_deg, A16, N);
    dense2_k<<<gd, 256, 0, stream>>>(H16, nullptr, nullptr,
                                     A16, wr1b, wl1b, b1b, nullptr,
                                     wl2, wr2, dtf, T, Q, N);

    // final: 2-wide gather + log_softmax (fp32 out)
    final_k<<<gN, 256, 0, stream>>>(T, Q, row_start, csr_src, inv_deg,
                                    b2, dtf, (float*)d_out, N);
}

// Round 19
// 463.291 us; speedup vs baseline: 1.0175x; 1.0175x over previous
//
#include <hip/hip_runtime.h>
#include <stdint.h>
#include <stddef.h>

#define DH 128
#define CHUNK 4096          // edges per partition block
#define PBK_SHIFT 9         // 512 nodes per bucket
#define NBKMAX 224          // supports N <= 114688

typedef short v8s __attribute__((ext_vector_type(8)));
typedef float v4f __attribute__((ext_vector_type(4)));
typedef float v2f __attribute__((ext_vector_type(2)));

static __device__ __forceinline__ float bf2f(uint16_t h) {
    union { uint32_t i; float f; } u; u.i = ((uint32_t)h) << 16; return u.f;
}
static __device__ __forceinline__ uint16_t f2bf(float f) {
    union { float f; uint32_t i; } u; u.f = f;
    uint32_t r = u.i + 0x7fffu + ((u.i >> 16) & 1u);  // RNE
    return (uint16_t)(r >> 16);
}
static __device__ __forceinline__ float loadf(const void* p, size_t i, bool f32) {
    return f32 ? ((const float*)p)[i] : bf2f(((const uint16_t*)p)[i]);
}
static __device__ __forceinline__ uint16_t pack_fp8x2(float a, float b) {
    return (uint16_t)(__builtin_amdgcn_cvt_pk_fp8_f32(a, b, 0, false) & 0xFFFF);
}

// ---------- histogram (+ dtype detect in block 0) ----------
__global__ void histA_k(const int* __restrict__ dst, const uint32_t* w, int* flag,
                        int* gh, int E, int n, int GH, int nbk) {
    __shared__ int h[NBKMAX];
    int t = threadIdx.x;
    if (blockIdx.x == 0 && t < 64) {
        int hits = 0;
        for (int k = 0; k < 4; ++k) {
            uint32_t u = w[t * 4 + k];
            int e = (u >> 7) & 0xFF;
            hits += (e >= 100 && e <= 130) ? 1 : 0;
        }
        for (int off = 32; off; off >>= 1) hits += __shfl_down(hits, off);
        if (t == 0) *flag = (hits >= 128) ? 0 : 1;   // 0 = bf16, 1 = fp32
    }
    int base = blockIdx.x * CHUNK;
    for (int i = t; i < NBKMAX; i += 256) h[i] = 0;
    __syncthreads();
    for (int it = 0; it < CHUNK / 256; ++it) {
        int e = base + it * 256 + t;
        if (e < E) {
            int d = dst[e];
            if ((unsigned)d < (unsigned)n) atomicAdd(&h[d >> PBK_SHIFT], 1);
        }
    }
    __syncthreads();
    for (int b = t; b < nbk; b += 256) gh[b * GH + blockIdx.x] = h[b];
}

// ---------- convert x -> bf16 (if fp32) + fp8 table, weights -> bf16 ----------
__global__ void cvtall_k(const void* x, const void* wl0, const void* wr0,
                         const void* wl1, const void* wr1, const void* b0,
                         const void* b1, const int* dt, uint16_t* xb,
                         uint16_t* xq8, uint16_t* wcvt, int nxh) {
    int i = blockIdx.x * 256 + threadIdx.x;
    bool f32 = (*dt != 0);
    if (i < nxh) {
        float v0, v1;
        if (f32) {
            const float2 v = ((const float2*)x)[i];
            v0 = v.x; v1 = v.y;
            ((uint32_t*)xb)[i] = (uint32_t)f2bf(v0) | ((uint32_t)f2bf(v1) << 16);
        } else {
            uint32_t u = ((const uint32_t*)x)[i];
            v0 = bf2f((uint16_t)u); v1 = bf2f((uint16_t)(u >> 16));
        }
        xq8[i] = pack_fp8x2(v0, v1);
        return;
    }
    int j = i - nxh;
    const void* src; int off;
    if      (j < 16384) { src = wl0; off = j; }
    else if (j < 32768) { src = wr0; off = j - 16384; }
    else if (j < 49152) { src = wl1; off = j - 32768; }
    else if (j < 65536) { src = wr1; off = j - 49152; }
    else if (j < 65664) { src = b0;  off = j - 65536; }
    else if (j < 65792) { src = b1;  off = j - 65664; }
    else return;
    wcvt[j] = f32 ? f2bf(((const float*)src)[off]) : ((const uint16_t*)src)[off];
}

// ---------- coalesced H16 -> fp8 table ----------
__global__ void cvt8_k(const uint32_t* __restrict__ H32, uint16_t* __restrict__ q8,
                       int nxh) {
    int i = blockIdx.x * 256 + threadIdx.x;
    if (i >= nxh) return;
    uint32_t u = H32[i];
    q8[i] = pack_fp8x2(bf2f((uint16_t)u), bf2f((uint16_t)(u >> 16)));
}

// ---------- scans over flattened bucket-major gh ----------
__global__ void scan1_k(const int* cnt, int* bsum, int n) {
    __shared__ int wt[4];
    int t = threadIdx.x, lane = t & 63, wv = t >> 6;
    int i = blockIdx.x * 256 + t;
    int v = (i < n) ? cnt[i] : 0;
    for (int off = 32; off; off >>= 1) v += __shfl_down(v, off);
    if (lane == 0) wt[wv] = v;
    __syncthreads();
    if (t == 0) bsum[blockIdx.x] = wt[0] + wt[1] + wt[2] + wt[3];
}

__global__ void scan2_k(const int* bsum, int* boff, int* row_n, int nb) {
    __shared__ int wt[4];
    __shared__ int carry_s;
    int t = threadIdx.x, lane = t & 63, wv = t >> 6;
    if (t == 0) carry_s = 0;
    __syncthreads();
    for (int base = 0; base < nb; base += 256) {
        int i = base + t;
        int c = (i < nb) ? bsum[i] : 0;
        int v = c;
        for (int off = 1; off < 64; off <<= 1) {
            int u = __shfl_up(v, off);
            if (lane >= off) v += u;
        }
        if (lane == 63) wt[wv] = v;
        __syncthreads();
        int woff = 0;
        for (int w = 0; w < wv; ++w) woff += wt[w];
        int total = wt[0] + wt[1] + wt[2] + wt[3];
        int carry = carry_s;
        if (i < nb) boff[i] = carry + woff + (v - c);
        __syncthreads();
        if (t == 0) carry_s = carry + total;
        __syncthreads();
    }
    if (t == 0) *row_n = carry_s;
}

__global__ void scanG3_k(const int* in, const int* boff, int* out, int n) {
    __shared__ int wt[4];
    int t = threadIdx.x, lane = t & 63, wv = t >> 6;
    int i = blockIdx.x * 256 + t;
    int c = (i < n) ? in[i] : 0;
    int v = c;
    for (int off = 1; off < 64; off <<= 1) {
        int u = __shfl_up(v, off);
        if (lane >= off) v += u;
    }
    if (lane == 63) wt[wv] = v;
    __syncthreads();
    int woff = 0;
    for (int w = 0; w < wv; ++w) woff += wt[w];
    if (i < n) out[i] = boff[blockIdx.x] + woff + (v - c);
}

// ---------- scatter with precomputed offsets (no global atomics) ----------
__global__ void scatB_k(const int* __restrict__ src, const int* __restrict__ dst,
                        const int* __restrict__ ghs, uint32_t* gbuf,
                        int E, int n, int GH, int nbk) {
    __shared__ int cur[NBKMAX];
    int t = threadIdx.x;
    int base = blockIdx.x * CHUNK;
    for (int b = t; b < nbk; b += 256) cur[b] = ghs[b * GH + blockIdx.x];
    __syncthreads();
    for (int it = 0; it < CHUNK / 256; ++it) {
        int e = base + it * 256 + t;
        if (e < E) {
            int d = dst[e];
            if ((unsigned)d < (unsigned)n) {
                int s = src[e];
                int slot = atomicAdd(&cur[d >> PBK_SHIFT], 1);
                uint32_t rec = ((uint32_t)(d & 511) << 17) | (uint32_t)s;
                __builtin_nontemporal_store(rec, &gbuf[slot]);
            }
        }
    }
}

// ---------- per-bucket regroup (512 nodes/bucket) ----------
__global__ void regroupC_k(const uint32_t* __restrict__ gbuf, const int* ghs,
                           const int* __restrict__ totalp, int GH,
                           int* row_start, float* inv_deg, int* csr_src,
                           int n, int nbk) {
    __shared__ int lcnt[512];
    __shared__ int rs[512];
    __shared__ int wsum[4];
    int b = blockIdx.x, t = threadIdx.x, lane = t & 63, wv = t >> 6;
    int node0 = b << PBK_SHIFT;
    int nn = n - node0; if (nn > 512) nn = 512;
    int start = ghs[b * GH];
    int end = (b + 1 < nbk) ? ghs[(b + 1) * GH] : *totalp;
    for (int i = t; i < 512; i += 256) lcnt[i] = 0;
    __syncthreads();
    for (int i = start + t; i < end; i += 256)
        atomicAdd(&lcnt[gbuf[i] >> 17], 1);
    __syncthreads();
    int c0 = lcnt[2 * t], c1 = lcnt[2 * t + 1];
    int s = c0 + c1;
    int v = s;
    for (int off = 1; off < 64; off <<= 1) {
        int u = __shfl_up(v, off);
        if (lane >= off) v += u;
    }
    if (lane == 63) wsum[wv] = v;
    __syncthreads();
    int woff = 0;
    for (int w = 0; w < wv; ++w) woff += wsum[w];
    int ex = woff + (v - s);
    rs[2 * t]     = ex;
    rs[2 * t + 1] = ex + c0;
    __syncthreads();
    for (int i = t; i < nn; i += 256) {
        row_start[node0 + i] = start + rs[i];
        inv_deg[node0 + i] = 1.0f / fmaxf((float)lcnt[i], 1.0f);
    }
    __syncthreads();
    for (int i = t; i < 512; i += 256) lcnt[i] = 0;   // reuse as cursors
    __syncthreads();
    for (int i = start + t; i < end; i += 256) {
        uint32_t rec = gbuf[i];
        int local = rec >> 17;
        int sv = rec & 0x1FFFF;
        int rank = atomicAdd(&lcnt[local], 1);
        csr_src[start + rs[local] + rank] = sv;
    }
}

// ---------- mean aggregation over FP8 table: one wave/node, 8 edges/iter ----------
__global__ void agg_k(const uint8_t* __restrict__ feat8,
                      const int* csr_src, const int* row_start,
                      const float* inv_deg, uint16_t* A, int n) {
    int wave = threadIdx.x >> 6, lane = threadIdx.x & 63;
    int node = blockIdx.x * 4 + wave;
    if (node >= n) return;
    int seg = lane & 7, sub = lane >> 3;
    int e0 = row_start[node], e1 = row_start[node + 1];
    float acc[16];
#pragma unroll
    for (int i = 0; i < 16; ++i) acc[i] = 0.f;
    for (int e = e0 + sub; e < e1; e += 8) {
        int s = csr_src[e];
        if ((unsigned)s >= (unsigned)n) continue;
        uint4 u = *(const uint4*)(feat8 + (size_t)s * 128 + seg * 16);
        v2f p;
        p = __builtin_amdgcn_cvt_pk_f32_fp8(u.x, false); acc[0]  += p.x; acc[1]  += p.y;
        p = __builtin_amdgcn_cvt_pk_f32_fp8(u.x, true);  acc[2]  += p.x; acc[3]  += p.y;
        p = __builtin_amdgcn_cvt_pk_f32_fp8(u.y, false); acc[4]  += p.x; acc[5]  += p.y;
        p = __builtin_amdgcn_cvt_pk_f32_fp8(u.y, true);  acc[6]  += p.x; acc[7]  += p.y;
        p = __builtin_amdgcn_cvt_pk_f32_fp8(u.z, false); acc[8]  += p.x; acc[9]  += p.y;
        p = __builtin_amdgcn_cvt_pk_f32_fp8(u.z, true);  acc[10] += p.x; acc[11] += p.y;
        p = __builtin_amdgcn_cvt_pk_f32_fp8(u.w, false); acc[12] += p.x; acc[13] += p.y;
        p = __builtin_amdgcn_cvt_pk_f32_fp8(u.w, true);  acc[14] += p.x; acc[15] += p.y;
    }
#pragma unroll
    for (int i = 0; i < 16; ++i) {
        acc[i] += __shfl_down(acc[i], 32);
        acc[i] += __shfl_down(acc[i], 16);
        acc[i] += __shfl_down(acc[i], 8);
    }
    if (sub == 0) {
        float sc = inv_deg[node];
        uint4 o0, o1;
        o0.x = (uint32_t)f2bf(acc[0]*sc)  | ((uint32_t)f2bf(acc[1]*sc)  << 16);
        o0.y = (uint32_t)f2bf(acc[2]*sc)  | ((uint32_t)f2bf(acc[3]*sc)  << 16);
        o0.z = (uint32_t)f2bf(acc[4]*sc)  | ((uint32_t)f2bf(acc[5]*sc)  << 16);
        o0.w = (uint32_t)f2bf(acc[6]*sc)  | ((uint32_t)f2bf(acc[7]*sc)  << 16);
        o1.x = (uint32_t)f2bf(acc[8]*sc)  | ((uint32_t)f2bf(acc[9]*sc)  << 16);
        o1.y = (uint32_t)f2bf(acc[10]*sc) | ((uint32_t)f2bf(acc[11]*sc) << 16);
        o1.z = (uint32_t)f2bf(acc[12]*sc) | ((uint32_t)f2bf(acc[13]*sc) << 16);
        o1.w = (uint32_t)f2bf(acc[14]*sc) | ((uint32_t)f2bf(acc[15]*sc) << 16);
        uint4* dst = (uint4*)A + (size_t)node * 16 + seg * 2;
        dst[0] = o0;
        dst[1] = o1;
    }
}

// ---------- fused dual MFMA dense, nt-pair unrolled epilogue ----------
// Both 16-col tiles of each 64B H-line are computed together and stored
// back-to-back, so L2 sees fully-dirty lines (fixes the 2.5x write amp
// diagnosed in R18: 32B partial-line stores separated by ~4KB of reads).
__global__ void dense2_k(const uint16_t* __restrict__ X,
                         const uint16_t* __restrict__ Xalt, const int* xdt,
                         const uint16_t* __restrict__ A,
                         const uint16_t* __restrict__ Wr,
                         const uint16_t* __restrict__ Wl,
                         const uint16_t* __restrict__ bias,
                         uint16_t* __restrict__ H,
                         const void* wl2, const void* wr2, const int* wdt,
                         float* T, float* Q, int n) {
    const int lane = threadIdx.x & 63;
    const int wv = threadIdx.x >> 6;
    const int m0 = blockIdx.x * 128 + wv * 32;
    if (m0 >= n) return;
    const uint16_t* Xs = X;
    if (xdt != nullptr && *xdt == 0) Xs = Xalt;
    const bool tq = (T != nullptr);
    const bool wf = tq && (*wdt != 0);
    const int row16 = lane & 15, quad = lane >> 4;
    int mr0 = m0 + row16;      int ml0 = (mr0 < n) ? mr0 : (n - 1);
    int mr1 = m0 + 16 + row16; int ml1 = (mr1 < n) ? mr1 : (n - 1);
    v8s ax0[4], aa0[4], ax1[4], aa1[4];
    const uint16_t* xr0 = Xs + (size_t)ml0 * DH + quad * 8;
    const uint16_t* ar0 = A  + (size_t)ml0 * DH + quad * 8;
    const uint16_t* xr1 = Xs + (size_t)ml1 * DH + quad * 8;
    const uint16_t* ar1 = A  + (size_t)ml1 * DH + quad * 8;
#pragma unroll
    for (int kt = 0; kt < 4; ++kt) {
        ax0[kt] = *(const v8s*)(xr0 + kt * 32);
        aa0[kt] = *(const v8s*)(ar0 + kt * 32);
        ax1[kt] = *(const v8s*)(xr1 + kt * 32);
        aa1[kt] = *(const v8s*)(ar1 + kt * 32);
    }
    float tqa[4][8];   // [T0,T1,Q0,Q1][row slot]
    if (tq) {
#pragma unroll
        for (int a = 0; a < 4; ++a)
#pragma unroll
            for (int j = 0; j < 8; ++j) tqa[a][j] = 0.f;
    }
#pragma unroll
    for (int np = 0; np < 4; ++np) {
        v4f a0A = {0.f,0.f,0.f,0.f}, a1A = {0.f,0.f,0.f,0.f};
        v4f a0B = {0.f,0.f,0.f,0.f}, a1B = {0.f,0.f,0.f,0.f};
        const uint16_t* wrrA = Wr + (size_t)(np * 32 + row16) * DH + quad * 8;
        const uint16_t* wlrA = Wl + (size_t)(np * 32 + row16) * DH + quad * 8;
        const uint16_t* wrrB = wrrA + 16 * DH;
        const uint16_t* wlrB = wlrA + 16 * DH;
#pragma unroll
        for (int kt = 0; kt < 4; ++kt) {
            v8s brA = *(const v8s*)(wrrA + kt * 32);
            a0A = __builtin_amdgcn_mfma_f32_16x16x32_bf16(ax0[kt], brA, a0A, 0, 0, 0);
            a1A = __builtin_amdgcn_mfma_f32_16x16x32_bf16(ax1[kt], brA, a1A, 0, 0, 0);
            v8s blA = *(const v8s*)(wlrA + kt * 32);
            a0A = __builtin_amdgcn_mfma_f32_16x16x32_bf16(aa0[kt], blA, a0A, 0, 0, 0);
            a1A = __builtin_amdgcn_mfma_f32_16x16x32_bf16(aa1[kt], blA, a1A, 0, 0, 0);
            v8s brB = *(const v8s*)(wrrB + kt * 32);
            a0B = __builtin_amdgcn_mfma_f32_16x16x32_bf16(ax0[kt], brB, a0B, 0, 0, 0);
            a1B = __builtin_amdgcn_mfma_f32_16x16x32_bf16(ax1[kt], brB, a1B, 0, 0, 0);
            v8s blB = *(const v8s*)(wlrB + kt * 32);
            a0B = __builtin_amdgcn_mfma_f32_16x16x32_bf16(aa0[kt], blB, a0B, 0, 0, 0);
            a1B = __builtin_amdgcn_mfma_f32_16x16x32_bf16(aa1[kt], blB, a1B, 0, 0, 0);
        }
        int oA = np * 32 + row16, oB = oA + 16;
        float boA = bf2f(bias[oA]), boB = bf2f(bias[oB]);
        float wl2_0A = 0.f, wl2_1A = 0.f, wr2_0A = 0.f, wr2_1A = 0.f;
        float wl2_0B = 0.f, wl2_1B = 0.f, wr2_0B = 0.f, wr2_1B = 0.f;
        if (tq) {
            wl2_0A = loadf(wl2, oA, wf);  wl2_1A = loadf(wl2, 128 + oA, wf);
            wr2_0A = loadf(wr2, oA, wf);  wr2_1A = loadf(wr2, 128 + oA, wf);
            wl2_0B = loadf(wl2, oB, wf);  wl2_1B = loadf(wl2, 128 + oB, wf);
            wr2_0B = loadf(wr2, oB, wf);  wr2_1B = loadf(wr2, 128 + oB, wf);
        }
#pragma unroll
        for (int r = 0; r < 4; ++r) {
            int m = m0 + quad * 4 + r;
            int m2 = m0 + 16 + quad * 4 + r;
            float h0A = fmaxf(a0A[r] + boA, 0.0f);
            float h0B = fmaxf(a0B[r] + boB, 0.0f);
            float h1A = fmaxf(a1A[r] + boA, 0.0f);
            float h1B = fmaxf(a1B[r] + boB, 0.0f);
            if (tq) {
                tqa[0][r] += h0A * wl2_0A + h0B * wl2_0B;
                tqa[1][r] += h0A * wl2_1A + h0B * wl2_1B;
                tqa[2][r] += h0A * wr2_0A + h0B * wr2_0B;
                tqa[3][r] += h0A * wr2_1A + h0B * wr2_1B;
                tqa[0][4 + r] += h1A * wl2_0A + h1B * wl2_0B;
                tqa[1][4 + r] += h1A * wl2_1A + h1B * wl2_1B;
                tqa[2][4 + r] += h1A * wr2_0A + h1B * wr2_0B;
                tqa[3][4 + r] += h1A * wr2_1A + h1B * wr2_1B;
            } else {
                if (m < n) {        // both tiles of one 64B line, adjacent stores
                    H[(size_t)m * DH + oA] = f2bf(h0A);
                    H[(size_t)m * DH + oB] = f2bf(h0B);
                }
                if (m2 < n) {
                    H[(size_t)m2 * DH + oA] = f2bf(h1A);
                    H[(size_t)m2 * DH + oB] = f2bf(h1B);
                }
            }
        }
    }
    if (tq) {
#pragma unroll
        for (int mbit = 1; mbit < 16; mbit <<= 1)
#pragma unroll
            for (int a = 0; a < 4; ++a)
#pragma unroll
                for (int j = 0; j < 8; ++j)
                    tqa[a][j] += __shfl_xor(tqa[a][j], mbit);
        if (row16 == 0) {
#pragma unroll
            for (int r = 0; r < 4; ++r) {
                int m = m0 + quad * 4 + r;
                if (m < n) {
                    T[(size_t)m * 2]     = tqa[0][r];
                    T[(size_t)m * 2 + 1] = tqa[1][r];
                    Q[(size_t)m * 2]     = tqa[2][r];
                    Q[(size_t)m * 2 + 1] = tqa[3][r];
                }
                int m2 = m0 + 16 + quad * 4 + r;
                if (m2 < n) {
                    T[(size_t)m2 * 2]     = tqa[0][4 + r];
                    T[(size_t)m2 * 2 + 1] = tqa[1][4 + r];
                    Q[(size_t)m2 * 2]     = tqa[2][4 + r];
                    Q[(size_t)m2 * 2 + 1] = tqa[3][4 + r];
                }
            }
        }
    }
}

// ---------- final: 2-wide CSR gather + log_softmax, fp32 out ----------
__global__ void final_k(const float* T, const float* Q, const int* row_start,
                        const int* csr_src, const float* inv_deg,
                        const void* b2, const int* wdt, float* out, int n) {
    int i = blockIdx.x * 256 + threadIdx.x;
    if (i >= n) return;
    bool f32 = (*wdt != 0);
    int e0 = row_start[i], e1 = row_start[i + 1];
    float s0 = 0.f, s1 = 0.f;
    const float2* T2 = (const float2*)T;
    for (int e = e0; e < e1; ++e) {
        int j = csr_src[e];
        if ((unsigned)j >= (unsigned)n) continue;
        float2 tv = T2[j];
        s0 += tv.x;
        s1 += tv.y;
    }
    float sc = inv_deg[i];
    float l0 = s0 * sc + loadf(b2, 0, f32) + Q[(size_t)i * 2];
    float l1 = s1 * sc + loadf(b2, 1, f32) + Q[(size_t)i * 2 + 1];
    float m = fmaxf(l0, l1);
    float lse = m + logf(expf(l0 - m) + expf(l1 - m));
    out[(size_t)i * 2]     = l0 - lse;
    out[(size_t)i * 2 + 1] = l1 - lse;
}

extern "C" void kernel_launch(void* const* d_in, const int* in_sizes, int n_in,
                              void* d_out, int out_size, void* d_ws, size_t ws_size,
                              hipStream_t stream) {
    int ix, iwl0, ib0, iwr0, iwl1, ib1, iwr1, iwl2, ib2, iwr2, iesrc, iedst;
    if (in_sizes[0] < 100000) {  // sorted-keys fallback
        ib0 = 0; ib1 = 1; ib2 = 2; iedst = 3; iesrc = 4;
        iwl0 = 5; iwl1 = 6; iwl2 = 7; iwr0 = 8; iwr1 = 9; iwr2 = 10; ix = 11;
    } else {                     // dict-insertion order (confirmed R7-R18)
        ix = 0; iwl0 = 1; ib0 = 2; iwr0 = 3; iwl1 = 4; ib1 = 5;
        iwr1 = 6; iwl2 = 7; ib2 = 8; iwr2 = 9; iesrc = 10; iedst = 11;
    }
    const void* x   = d_in[ix];
    const void* wl0 = d_in[iwl0];
    const void* b0  = d_in[ib0];
    const void* wr0 = d_in[iwr0];
    const void* wl1 = d_in[iwl1];
    const void* b1  = d_in[ib1];
    const void* wr1 = d_in[iwr1];
    const void* wl2 = d_in[iwl2];
    const void* b2  = d_in[ib2];
    const void* wr2 = d_in[iwr2];
    const int* esrc = (const int*)d_in[iesrc];
    const int* edst = (const int*)d_in[iedst];
    const int N = out_size / 2;
    const int E = in_sizes[iesrc];
    (void)n_in; (void)ws_size;

    char* ws = (char*)d_ws;
    size_t off = 0;
    auto carve = [&](size_t bytes) -> char* {
        char* p = ws + off;
        off = (off + bytes + 255) & ~(size_t)255;
        return p;
    };
    int gN = (N + 255) / 256;
    int GH = (E + CHUNK - 1) / CHUNK;
    int nbk = (N + 511) >> PBK_SHIFT;
    int n_scan = nbk * GH;
    int gS = (n_scan + 255) / 256;
    int* dtf        = (int*)   carve(256);
    int* gh         = (int*)   carve((size_t)n_scan * 4);
    int* ghs        = (int*)   carve((size_t)n_scan * 4);
    int* bsum       = (int*)   carve((size_t)gS * 4);
    int* boff       = (int*)   carve((size_t)gS * 4);
    uint32_t* gbuf  = (uint32_t*)carve((size_t)E * 4);
    int* row_start  = (int*)   carve((size_t)(N + 1) * 4);
    float* inv_deg  = (float*) carve((size_t)N * 4);
    int* csr_src    = (int*)   carve((size_t)E * 4);
    uint16_t* A16   = (uint16_t*)carve((size_t)N * DH * 2);
    uint16_t* H16   = (uint16_t*)carve((size_t)N * DH * 2);
    uint16_t* xb    = (uint16_t*)carve((size_t)N * DH * 2);
    uint8_t*  xq8   = (uint8_t*) carve((size_t)N * DH);
    uint8_t*  hq8   = (uint8_t*) carve((size_t)N * DH);
    uint16_t* wcvt  = (uint16_t*)carve(65792 * 2);
    float* T        = (float*) carve((size_t)N * 2 * 4);
    float* Q        = (float*) carve((size_t)N * 2 * 4);
    uint16_t* wl0b = wcvt;
    uint16_t* wr0b = wcvt + 16384;
    uint16_t* wl1b = wcvt + 32768;
    uint16_t* wr1b = wcvt + 49152;
    uint16_t* b0b  = wcvt + 65536;
    uint16_t* b1b  = wcvt + 65664;

    int ga = (N + 3) / 4;
    int gd = (N + 127) / 128;
    int nxh = (N * DH) / 2;
    int gc = (nxh + 65792 + 255) / 256;
    int g8 = (nxh + 255) / 256;

    // histogram (+dtype detect), then conversions (x pairs -> bf16 + fp8)
    histA_k<<<GH, 256, 0, stream>>>(edst, (const uint32_t*)wl0, dtf, gh, E, N, GH, nbk);
    cvtall_k<<<gc, 256, 0, stream>>>(x, wl0, wr0, wl1, wr1, b0, b1, dtf,
                                     xb, (uint16_t*)xq8, wcvt, nxh);

    // CSR build: radix partition with precomputed offsets
    scan1_k<<<gS, 256, 0, stream>>>(gh, bsum, n_scan);
    scan2_k<<<1, 256, 0, stream>>>(bsum, boff, &row_start[N], gS);
    scanG3_k<<<gS, 256, 0, stream>>>(gh, boff, ghs, n_scan);
    scatB_k<<<GH, 256, 0, stream>>>(esrc, edst, ghs, gbuf, E, N, GH, nbk);
    regroupC_k<<<nbk, 256, 0, stream>>>(gbuf, ghs, &row_start[N], GH,
                                        row_start, inv_deg, csr_src, N, nbk);

    // layer 0: A = agg(x_fp8); H16 = relu(x@Wr0^T + A@Wl0^T + b0)
    agg_k<<<ga, 256, 0, stream>>>(xq8, csr_src, row_start, inv_deg, A16, N);
    dense2_k<<<gd, 256, 0, stream>>>(xb, (const uint16_t*)x, dtf,
                                     A16, wr0b, wl0b, b0b, H16,
                                     nullptr, nullptr, nullptr,
                                     nullptr, nullptr, N);

    // coalesced H16 -> fp8 for layer-1 gather
    cvt8_k<<<g8, 256, 0, stream>>>((const uint32_t*)H16, (uint16_t*)hq8, nxh);

    // layer 1: A = agg(H_fp8); fused T/Q heads only (H store is dead)
    agg_k<<<ga, 256, 0, stream>>>(hq8, csr_src, row_start, inv_deg, A16, N);
    dense2_k<<<gd, 256, 0, stream>>>(H16, nullptr, nullptr,
                                     A16, wr1b, wl1b, b1b, nullptr,
                                     wl2, wr2, dtf, T, Q, N);

    // final: 2-wide gather + log_softmax (fp32 out)
    final_k<<<gN, 256, 0, stream>>>(T, Q, row_start, csr_src, inv_deg,
                                    b2, dtf, (float*)d_out, N);
}